// Round 6
// baseline (190.307 us; speedup 1.0000x reference)
//
#include <hip/hip_runtime.h>

typedef _Float16 f16;
typedef _Float16 f16x8 __attribute__((ext_vector_type(8)));
typedef __bf16 bf16x8 __attribute__((ext_vector_type(8)));
typedef __bf16 bf16x4 __attribute__((ext_vector_type(4)));
typedef float floatx4 __attribute__((ext_vector_type(4)));
typedef unsigned short u16;
typedef unsigned int u32;

#define B_N   8
#define T_SEQ 4096
#define DIM   64
#define QT    32    // q rows per block (all 4 waves share them; waves split keys)
#define KT    128   // keys per iter (32 per wave)
#define PSTR  40    // P row stride in u16 (80 B; rows 16B-aligned)
#define OSTR  68    // epilogue O row stride in f32 (272 B = 17*16B aligned)
#define XSTR  72    // prep LDS row stride in u16 (144 B)
#define LOG2E 1.44269504f

#if __has_builtin(__builtin_amdgcn_exp2f)
#define EXP2(x) __builtin_amdgcn_exp2f(x)
#else
#define EXP2(x) exp2f(x)
#endif

// ---- prep: Kh=f16(X), Qh=f16(log2e * X@W), Vt=bf16(X^T) ----
__launch_bounds__(256, 2)
__global__ void prep_kernel(const float* __restrict__ X, const float* __restrict__ W,
                            u16* __restrict__ Kh, u16* __restrict__ Qh,
                            u16* __restrict__ Vt) {
  __shared__ __attribute__((aligned(16))) u16 Xs[DIM * XSTR];  // f16 X tile [t][d]
  __shared__ __attribute__((aligned(16))) u16 Wt[DIM * XSTR];  // f16 W^T [e][d]
  const int tid = threadIdx.x;
  const int lane = tid & 63, w = tid >> 6, qd = lane >> 4, ln = lane & 15;
  const int b = blockIdx.y;
  const int t0 = blockIdx.x * 64;
  const long xbase = ((long)b * T_SEQ + t0) * DIM;

  {
    const int r = tid >> 2, c0 = (tid & 3) * 16;
    float v[16];
#pragma unroll
    for (int i = 0; i < 4; i++)
      *(float4*)&v[i * 4] = *(const float4*)(X + xbase + (long)r * DIM + c0 + i * 4);
    u16 h[16];
#pragma unroll
    for (int j = 0; j < 16; j++) h[j] = __builtin_bit_cast(u16, (f16)v[j]);
    u16* kd = Kh + xbase + (long)r * DIM + c0;
    *(uint4*)kd = *(uint4*)&h[0];
    *(uint4*)(kd + 8) = *(uint4*)&h[8];
    *(uint4*)&Xs[r * XSTR + c0] = *(uint4*)&h[0];
    *(uint4*)&Xs[r * XSTR + c0 + 8] = *(uint4*)&h[8];
    // W^T (f16) — d = r, e = c0+j
    float wv[16];
#pragma unroll
    for (int i = 0; i < 4; i++)
      *(float4*)&wv[i * 4] = *(const float4*)(W + r * DIM + c0 + i * 4);
#pragma unroll
    for (int j = 0; j < 16; j++) Wt[(c0 + j) * XSTR + r] = __builtin_bit_cast(u16, (f16)wv[j]);
  }
  __syncthreads();

  // Q = X@W via MFMA: wave w owns rows wq..wq+15
  {
    const int wq = w * 16;
    floatx4 acc[4];
#pragma unroll
    for (int ct = 0; ct < 4; ct++) acc[ct] = (floatx4)0.0f;
#pragma unroll
    for (int ks = 0; ks < 2; ks++) {
      f16x8 aX = *(const f16x8*)&Xs[(wq + ln) * XSTR + ks * 32 + qd * 8];
#pragma unroll
      for (int ct = 0; ct < 4; ct++) {
        f16x8 bW = *(const f16x8*)&Wt[(ct * 16 + ln) * XSTR + ks * 32 + qd * 8];
        acc[ct] = __builtin_amdgcn_mfma_f32_16x16x32_f16(aX, bW, acc[ct], 0, 0, 0);
      }
    }
#pragma unroll
    for (int ct = 0; ct < 4; ct++)
#pragma unroll
      for (int r = 0; r < 4; r++)
        Qh[xbase + (long)(wq + qd * 4 + r) * DIM + ct * 16 + ln] =
            __builtin_bit_cast(u16, (f16)(acc[ct][r] * LOG2E));
  }

  // Vt[b][d][t] = bf16(X[t][d])
  {
    const int d = tid >> 2, tg = tid & 3;
    u16 vb[16];
#pragma unroll
    for (int j = 0; j < 16; j++) {
      f16 hv = __builtin_bit_cast(f16, Xs[(tg * 16 + j) * XSTR + d]);
      vb[j] = __builtin_bit_cast(u16, (__bf16)(float)hv);
    }
    u16* vdst = Vt + ((long)b * DIM + d) * T_SEQ + t0 + tg * 16;
    *(uint4*)vdst = *(uint4*)&vb[0];
    *(uint4*)(vdst + 8) = *(uint4*)&vb[8];
  }
}

// ---- main: flash attention; waves split keys; S computed transposed ----
__launch_bounds__(256, 4)
__global__ void attn_kernel(const u16* __restrict__ Kh, const u16* __restrict__ Qh,
                            const u16* __restrict__ Vt, float* __restrict__ out) {
  // union: Ps (4 waves * 32 rows * PSTR u16 = 10240 B) | Opart (4*16*OSTR f32 = 17408 B)
  __shared__ __attribute__((aligned(16))) char smem[4 * 16 * OSTR * 4];
  __shared__ float lpart[4][QT];

  u16* Ps = (u16*)smem;
  float* Opart = (float*)smem;

  const int tid = threadIdx.x;
  const int lane = tid & 63;
  const int w = tid >> 6;
  const int qd = lane >> 4;
  const int ln = lane & 15;
  const int bid = blockIdx.x;
  const int b = bid & 7;                 // batch == XCD for L2 affinity
  const int q0 = (bid >> 3) * QT;
  const long bbase = (long)b * T_SEQ * DIM;

  const u16* pK = Kh + bbase + (long)(w * 32) * DIM;
  const u16* pV = Vt + (long)b * DIM * T_SEQ + w * 32;
  u16* Pw = Ps + w * (QT * PSTR);

  // Q A-fragments pinned (32 rows x 64 d)
  f16x8 aQ[2][2];
#pragma unroll
  for (int rb = 0; rb < 2; rb++)
#pragma unroll
    for (int ks = 0; ks < 2; ks++)
      aQ[rb][ks] = *(const f16x8*)(Qh + bbase + (long)(q0 + rb * 16 + ln) * DIM + ks * 32 + qd * 8);

  floatx4 O[2][4];
  float lrow[2] = {0.0f, 0.0f};
#pragma unroll
  for (int rb = 0; rb < 2; rb++)
#pragma unroll
    for (int cd = 0; cd < 4; cd++) O[rb][cd] = (floatx4)0.0f;

  for (int kt = 0; kt < T_SEQ / KT; kt++) {
    const long koff = (long)kt * KT * DIM;
    const int voff = kt * KT;
    // K B-fragments (wave's own 32 keys)
    f16x8 bK[2][2];
#pragma unroll
    for (int ct = 0; ct < 2; ct++)
#pragma unroll
      for (int ks = 0; ks < 2; ks++)
        bK[ct][ks] = *(const f16x8*)(pK + koff + (long)(ct * 16 + ln) * DIM + ks * 32 + qd * 8);
    // V^T B-fragments
    bf16x8 bV[4];
#pragma unroll
    for (int cd = 0; cd < 4; cd++)
      bV[cd] = *(const bf16x8*)(pV + (long)(cd * 16 + ln) * T_SEQ + voff + qd * 8);

    // S^T = K Q^T : D[k = ct*16+qd*4+r][q = rb*16+ln]
    floatx4 St[2][2];
#pragma unroll
    for (int ct = 0; ct < 2; ct++)
#pragma unroll
      for (int rb = 0; rb < 2; rb++) St[ct][rb] = (floatx4)0.0f;
#pragma unroll
    for (int ks = 0; ks < 2; ks++)
#pragma unroll
      for (int ct = 0; ct < 2; ct++)
#pragma unroll
        for (int rb = 0; rb < 2; rb++)
          St[ct][rb] = __builtin_amdgcn_mfma_f32_16x16x32_f16(bK[ct][ks], aQ[rb][ks], St[ct][rb], 0, 0, 0);

    // P = 2^S' (Q pre-scaled by log2e); per-lane l; k-contiguous b64 P-writes
#pragma unroll
    for (int rb = 0; rb < 2; rb++)
#pragma unroll
      for (int ct = 0; ct < 2; ct++) {
        bf16x4 pk;
#pragma unroll
        for (int r = 0; r < 4; r++) {
          float p = EXP2(St[ct][rb][r]);
          lrow[rb] += p;
          pk[r] = (__bf16)p;
        }
        *(uint2*)&Pw[(rb * 16 + ln) * PSTR + ct * 16 + qd * 4] = __builtin_bit_cast(uint2, pk);
      }

    // O += P V  (compiler inserts the lgkmcnt wait for the same-buffer dep)
#pragma unroll
    for (int rb = 0; rb < 2; rb++) {
      bf16x8 aP = *(const bf16x8*)&Pw[(rb * 16 + ln) * PSTR + qd * 8];
#pragma unroll
      for (int cd = 0; cd < 4; cd++)
        O[rb][cd] = __builtin_amdgcn_mfma_f32_16x16x32_bf16(aP, bV[cd], O[rb][cd], 0, 0, 0);
    }
  }

  // l: per-lane (q=ln) partials; reduce across qd lanes
#pragma unroll
  for (int rb = 0; rb < 2; rb++) {
    float v = lrow[rb];
    v += __shfl_xor(v, 16, 64);
    v += __shfl_xor(v, 32, 64);
    if (qd == 0) lpart[w][rb * 16 + ln] = v;
  }

  // epilogue: cross-wave O reduction, 2 rounds of 16 rows (Opart aliases Ps)
  const int erow = tid >> 4;
  const int ec0 = (tid & 15) * 4;
#pragma unroll 1
  for (int rb = 0; rb < 2; rb++) {
    __syncthreads();  // round 0: publishes lpart + retires all Ps reads
#pragma unroll
    for (int cd = 0; cd < 4; cd++)
#pragma unroll
      for (int r = 0; r < 4; r++)
        Opart[w * 16 * OSTR + (qd * 4 + r) * OSTR + cd * 16 + ln] = O[rb][cd][r];
    __syncthreads();
    float4 s0 = *(const float4*)&Opart[0 * 16 * OSTR + erow * OSTR + ec0];
    float4 s1 = *(const float4*)&Opart[1 * 16 * OSTR + erow * OSTR + ec0];
    float4 s2 = *(const float4*)&Opart[2 * 16 * OSTR + erow * OSTR + ec0];
    float4 s3 = *(const float4*)&Opart[3 * 16 * OSTR + erow * OSTR + ec0];
    float l = lpart[0][rb * 16 + erow] + lpart[1][rb * 16 + erow] +
              lpart[2][rb * 16 + erow] + lpart[3][rb * 16 + erow];
    float inv = 1.0f / l;
    float4 o;
    o.x = (s0.x + s1.x + s2.x + s3.x) * inv;
    o.y = (s0.y + s1.y + s2.y + s3.y) * inv;
    o.z = (s0.z + s1.z + s2.z + s3.z) * inv;
    o.w = (s0.w + s1.w + s2.w + s3.w) * inv;
    *(float4*)(out + bbase + (long)(q0 + rb * 16 + erow) * DIM + ec0) = o;
  }
}

extern "C" void kernel_launch(void* const* d_in, const int* in_sizes, int n_in,
                              void* d_out, int out_size, void* d_ws, size_t ws_size,
                              hipStream_t stream) {
  const float* X = (const float*)d_in[0];
  const float* W = (const float*)d_in[1];
  float* out = (float*)d_out;
  const size_t SZ = (size_t)B_N * T_SEQ * DIM * 2;  // 4 MB per u16 array
  u16* Kh = (u16*)d_ws;
  u16* Qh = (u16*)((char*)d_ws + SZ);
  u16* Vt = (u16*)((char*)d_ws + 2 * SZ);
  prep_kernel<<<dim3(T_SEQ / 64, B_N), 256, 0, stream>>>(X, W, Kh, Qh, Vt);
  attn_kernel<<<dim3(B_N * (T_SEQ / QT)), 256, 0, stream>>>(Kh, Qh, Vt, out);
}